// Round 3
// baseline (738.876 us; speedup 1.0000x reference)
//
#include <hip/hip_runtime.h>
#include <cstdint>
#include <cstddef>

#define M_DIM 2048
#define N_DIM 4096
#define K_DIM 20000
#define KP    20480                 /* K padded to multiple of 64 (zero-filled) */
#define KZ    10240                 /* K per split-K plane (2 planes) */
#define NITER 80                    /* (KZ/64) tiles / 2 tiles per iter */
#define WBT_BYTES  167772160UL      /* 4096*20480*2 : bf16 W^T (N x KP) */
#define XB_OFFSET  167772160UL      /* bf16 x (M x KP) after Wbt */
#define CP_OFFSET  251658240UL      /* 2x fp32 C-partials after xb */
#define ZBLK 2048                   /* zeroing blocks in fused zero+convert */

typedef __attribute__((ext_vector_type(8))) short short8;
typedef __attribute__((ext_vector_type(4))) float float4v;
typedef __attribute__((ext_vector_type(8))) unsigned short ushort8;

__device__ __forceinline__ unsigned short f2bf_rne(float f) {
    union { float f; unsigned int u; } v; v.f = f;
    unsigned int u = v.u;
    u += 0x7FFFu + ((u >> 16) & 1u);   // round-to-nearest-even
    return (unsigned short)(u >> 16);
}

__device__ __forceinline__ float bf2f(unsigned short h) {
    union { unsigned int u; float f; } v;
    v.u = ((unsigned int)h) << 16;
    return v.f;
}

__device__ __forceinline__ void gload_lds16(const void* g, void* l) {
    __builtin_amdgcn_global_load_lds(
        (const __attribute__((address_space(1))) void*)g,
        (__attribute__((address_space(3))) void*)l, 16, 0, 0);
}

// ---- 1. scatter-add COO directly into bf16 W^T (N_DIM x KP row-major) ----
__global__ void scatter_bf16_kernel(const float* __restrict__ kv,
                                    const int* __restrict__ ind,
                                    unsigned int* __restrict__ W, int nnz) {
    int t = blockIdx.x * blockDim.x + threadIdx.x;
    if (t >= nnz) return;
    int r = ind[2 * t];      // input_dim index (K)
    int c = ind[2 * t + 1];  // units index (N)
    float v = kv[t];
    size_t elem = (size_t)c * KP + r;      // bf16 element index in W^T
    unsigned int* word = &W[elem >> 1];
    const bool hi = (elem & 1) != 0;       // KP even -> rows never straddle words
    unsigned int old = __atomic_load_n(word, __ATOMIC_RELAXED);
    unsigned int assumed;
    do {
        assumed = old;
        unsigned short h = hi ? (unsigned short)(assumed >> 16)
                              : (unsigned short)(assumed & 0xFFFFu);
        unsigned short nh = f2bf_rne(bf2f(h) + v);
        unsigned int nw = hi ? ((assumed & 0x0000FFFFu) | ((unsigned int)nh << 16))
                             : ((assumed & 0xFFFF0000u) | (unsigned int)nh);
        old = atomicCAS(word, assumed, nw);
    } while (old != assumed);
}

// ---- 2. fused: zero Wbt (blocks < ZBLK) + fp32->bf16 convert of x ----
// zero: 2048 blocks x 256 thr x 20 float4 stores = 167.77 MB exactly.
// convert: one thread per 8 elements of the PADDED row (2560 slots, 2500 real).
__global__ void zero_convert_kernel(const float* __restrict__ src,
                                    unsigned short* __restrict__ dst,
                                    float4* __restrict__ wzero) {
    int b = blockIdx.x;
    if (b < ZBLK) {
        size_t t = (size_t)b * 256 + threadIdx.x;       // 524288 threads
        float4 z; z.x = 0.f; z.y = 0.f; z.z = 0.f; z.w = 0.f;
        #pragma unroll
        for (int i = 0; i < 20; ++i)
            wzero[t + (size_t)i * (ZBLK * 256)] = z;    // 10485760 chunks total
        return;
    }
    size_t t = (size_t)(b - ZBLK) * 256 + threadIdx.x;
    int row = (int)(t / 2560);
    int c8  = (int)(t % 2560);
    ushort8 o;
    if (c8 < 2500) {
        const float4* sv = (const float4*)(src + (size_t)row * K_DIM + (size_t)c8 * 8);
        float4 a = sv[0];
        float4 b2 = sv[1];
        o[0] = f2bf_rne(a.x);  o[1] = f2bf_rne(a.y);
        o[2] = f2bf_rne(a.z);  o[3] = f2bf_rne(a.w);
        o[4] = f2bf_rne(b2.x); o[5] = f2bf_rne(b2.y);
        o[6] = f2bf_rne(b2.z); o[7] = f2bf_rne(b2.w);
    } else {
        o = (ushort8)0;
    }
    *(ushort8*)(dst + (size_t)row * KP + (size_t)c8 * 8) = o;
}

// ---- 3. 256x256-tile split-K=2 GEMM, 8-phase schedule, fragment-order LDS ----
// A: M x KP bf16 row-major, Bt: N x KP bf16 row-major.
// 512 thr = 8 waves (2Mx4N), per-wave 128x64, BK=64, 2 K-tiles per iter.
// LDS 128 KiB, buffer = A[kh](2x16KB) + B[kh](2x16KB); each 16KB slab is 16
// groups of (16 rows x 64B) stored FRAGMENT-ORDER: [chunk][row][16B], so MFMA
// fragment lane l (chunk=l>>4,row=l&15) reads byte l*16 -> lane-LINEAR,
// zero bank conflicts under any HW lane grouping. Staging LDS dest stays
// linear (gload_lds requirement); the transpose is applied on the GLOBAL
// source lane mapping (same address set per gload -> identical coalescing).
// Per phase: {ds_read subtile, stage one 16KB quarter (2 gloads), s_barrier,
// lgkmcnt(0), setprio(1) 16 MFMA setprio(0), [vmcnt(8) at even phases],
// s_barrier}. vmcnt never drains in the main loop.
__global__ __launch_bounds__(512, 2) void gemm256_kernel(
    const unsigned short* __restrict__ A,
    const unsigned short* __restrict__ Bt,
    float* __restrict__ Cp) {

    __shared__ unsigned short L[65536];    // 131072 B

    const int t    = threadIdx.x;
    const int w    = t >> 6;
    const int l    = t & 63;
    const int quad = l >> 4;
    const int r16  = l & 15;
    const int wm   = w >> 2;               // 0..1
    const int wn   = w & 3;                // 0..3

    const int m0 = blockIdx.y * 256;
    const int n0 = blockIdx.x * 256;
    const size_t k0 = (size_t)blockIdx.z * KZ;

    // staging, fragment-order: per quarter (16KB = 16 groups of 16 rows),
    // wave w stages groups 2w,2w+1 (2 gloads). Lane l fetches global
    // row (l&15) of the group, k-chunk (l>>4); LDS dest is linear l*16.
    const int lr = l & 15;
    const int lc = l >> 4;
    const unsigned short* pA0 = A  + (size_t)(m0 + w * 32 + lr) * KP + k0 + lc * 8;
    const unsigned short* pA1 = pA0 + (size_t)16 * KP;
    const unsigned short* pB0 = Bt + (size_t)(n0 + w * 32 + lr) * KP + k0 + lc * 8;
    const unsigned short* pB1 = pB0 + (size_t)16 * KP;

    char* Lb = (char*)L;
    const int wdst = w << 11;              // wave's 2KB within a quarter

    // buffer layout (byte offsets): buf b at b*65536
    //   A kh0 [0,16K)  A kh1 [16K,32K)  B kh0 [32K,48K)  B kh1 [48K,64K)
#define STAGE_A(REG) do { \
    gload_lds16(pA0, Lb + (REG) + wdst); \
    gload_lds16(pA1, Lb + (REG) + wdst + 1024); \
    pA0 += 32; pA1 += 32; } while (0)
#define STAGE_B(REG) do { \
    gload_lds16(pB0, Lb + (REG) + wdst); \
    gload_lds16(pB1, Lb + (REG) + wdst + 1024); \
    pB0 += 32; pB1 += 32; } while (0)

    // fragment offsets (fragment-order): group gA = wm*8 + mh*4 + i,
    // byte = gA*1024 + l*16;  B: group gB = wn*4 + j (+32768 slab base).
    const int aoff = wm * 8192 + l * 16;                 // + mh*4096 + i*1024
    const int boff = 32768 + wn * 4096 + l * 16;         // + j*1024

    float4v acc[8][4];
#pragma unroll
    for (int i = 0; i < 8; ++i)
#pragma unroll
        for (int j = 0; j < 4; ++j)
            acc[i][j] = (float4v){0.f, 0.f, 0.f, 0.f};

    short8 bfr[4], af[4];

#define VM8 asm volatile("s_waitcnt vmcnt(8)" ::: "memory")
#define VMNONE ((void)0)

    // BASEOFF = buf*65536 + kh*16384 (A slab base; B slab = +32768 via boff)
#define PHASE(BASEOFF, MH, LOADB, STG, VM) do { \
    const char* base_ = Lb + (BASEOFF); \
    if (LOADB) { \
        _Pragma("unroll") \
        for (int j = 0; j < 4; ++j) \
            bfr[j] = *(const short8*)(base_ + boff + j * 1024); \
    } \
    _Pragma("unroll") \
    for (int i = 0; i < 4; ++i) \
        af[i] = *(const short8*)(base_ + aoff + (MH) * 4096 + i * 1024); \
    STG; \
    __builtin_amdgcn_s_barrier(); \
    asm volatile("s_waitcnt lgkmcnt(0)" ::: "memory"); \
    __builtin_amdgcn_s_setprio(1); \
    _Pragma("unroll") \
    for (int i = 0; i < 4; ++i) \
        _Pragma("unroll") \
        for (int j = 0; j < 4; ++j) \
            acc[(MH) * 4 + i][j] = __builtin_amdgcn_mfma_f32_16x16x32_bf16( \
                af[i], bfr[j], acc[(MH) * 4 + i][j], 0, 0, 0); \
    __builtin_amdgcn_s_setprio(0); \
    VM; \
    __builtin_amdgcn_s_barrier(); \
} while (0)

    // prologue: tile0 full + tile1 kh0 (12 loads); wait tile0.kh0 (oldest 4)
    STAGE_A(0);     STAGE_B(32768);
    STAGE_A(16384); STAGE_B(49152);
    STAGE_A(65536); STAGE_B(98304);
    asm volatile("s_waitcnt vmcnt(8)" ::: "memory");
    __builtin_amdgcn_s_barrier();

    // main loop: iter computes tiles 2i (buf0) and 2i+1 (buf1).
    // staging stream per iter: P1 t(2i+1).A1, P2 t(2i+1).B1, P3 t(2i+2).A0,
    // P4 .B0, P5 .A1, P6 .B1, P7 t(2i+3).A0, P8 .B0 — each lands in a slab
    // freed one-or-more barriers earlier; vmcnt(8) at even phases guarantees
    // the next odd phase's slab (staged 4 phases ago) has landed.
    // Final iter stages past the K range: reads stay inside the workspace.
#pragma unroll 1
    for (int it = 0; it < NITER; ++it) {
        PHASE(0,     0, true,  STAGE_A(81920),  VMNONE);   // P1: buf0 kh0, mh0
        PHASE(0,     1, false, STAGE_B(114688), VM8);      // P2: buf0 kh0, mh1
        PHASE(16384, 0, true,  STAGE_A(0),      VMNONE);   // P3: buf0 kh1, mh0
        PHASE(16384, 1, false, STAGE_B(32768),  VM8);      // P4: buf0 kh1, mh1
        PHASE(65536, 0, true,  STAGE_A(16384),  VMNONE);   // P5: buf1 kh0, mh0
        PHASE(65536, 1, false, STAGE_B(49152),  VM8);      // P6: buf1 kh0, mh1
        PHASE(81920, 0, true,  STAGE_A(65536),  VMNONE);   // P7: buf1 kh1, mh0
        PHASE(81920, 1, false, STAGE_B(98304),  VM8);      // P8: buf1 kh1, mh1
    }
    // drain in-flight LDS DMA before wave exit
    asm volatile("s_waitcnt vmcnt(0)" ::: "memory");

    // epilogue: raw fp32 partial; C/D layout: col = lane&15, row = quad*4 + reg
    float* Cz = Cp + (size_t)blockIdx.z * ((size_t)M_DIM * N_DIM);
#pragma unroll
    for (int i = 0; i < 8; ++i) {
        const int row = m0 + wm * 128 + i * 16 + quad * 4;
#pragma unroll
        for (int j = 0; j < 4; ++j) {
            const int col = n0 + wn * 64 + j * 16 + r16;
#pragma unroll
            for (int r = 0; r < 4; ++r)
                Cz[(size_t)(row + r) * N_DIM + col] = acc[i][j][r];
        }
    }
#undef PHASE
#undef STAGE_A
#undef STAGE_B
#undef VM8
#undef VMNONE
}

// ---- 4. combine: out = tanh(C0 + C1 + bias), float4 vectorized ----
__global__ void combine_kernel(const float* __restrict__ Cp,
                               const float* __restrict__ bias,
                               float* __restrict__ out) {
    size_t t = (size_t)blockIdx.x * 256 + threadIdx.x;       // per float4
    const size_t stride = (size_t)M_DIM * N_DIM / 4;
    float4 a = ((const float4*)Cp)[t];
    float4 b = ((const float4*)Cp)[t + stride];
    float4 bv = ((const float4*)bias)[t & (N_DIM / 4 - 1)];
    float4 o;
    o.x = tanhf(a.x + b.x + bv.x);
    o.y = tanhf(a.y + b.y + bv.y);
    o.z = tanhf(a.z + b.z + bv.z);
    o.w = tanhf(a.w + b.w + bv.w);
    ((float4*)out)[t] = o;
}

extern "C" void kernel_launch(void* const* d_in, const int* in_sizes, int n_in,
                              void* d_out, int out_size, void* d_ws, size_t ws_size,
                              hipStream_t stream) {
    const float* x    = (const float*)d_in[0];
    const float* kv   = (const float*)d_in[1];
    const float* bias = (const float*)d_in[2];
    const int*   ind  = (const int*)d_in[3];
    const int nnz = in_sizes[1];

    unsigned short* Wbt = (unsigned short*)d_ws;                        // bf16 W^T (N x KP)
    unsigned short* xb  = (unsigned short*)((char*)d_ws + XB_OFFSET);   // bf16 x (M x KP)
    float* Cp = (float*)((char*)d_ws + CP_OFFSET);                      // 2 x 33.55 MB partials

    // 1. fused: zero Wbt + convert x (independent outputs, one launch)
    zero_convert_kernel<<<ZBLK + (M_DIM * (KP / 8)) / 256, 256, 0, stream>>>(
        x, xb, (float4*)Wbt);
    // 2. scatter-add straight into bf16 W^T (CAS on 16-bit halves)
    scatter_bf16_kernel<<<(nnz + 255) / 256, 256, 0, stream>>>(
        kv, ind, (unsigned int*)Wbt, nnz);
    // 3. split-K=2 GEMM partials, 256x256 tiles, 1 WG/CU
    gemm256_kernel<<<dim3(N_DIM / 256, M_DIM / 256, 2), 512, 0, stream>>>(
        xb, Wbt, Cp);
    // 4. combine + bias + tanh
    combine_kernel<<<(M_DIM * N_DIM) / (256 * 4), 256, 0, stream>>>(
        Cp, bias, (float*)d_out);
}

// Round 4
// 640.907 us; speedup vs baseline: 1.1529x; 1.1529x over previous
//
#include <hip/hip_runtime.h>
#include <cstdint>
#include <cstddef>

#define M_DIM 2048
#define N_DIM 4096
#define K_DIM 20000
#define KP    20480                 /* K padded to multiple of 64 (zero-filled) */
#define KZ    10240                 /* K per split-K plane (2 planes) */
#define NTILE 160                   /* KZ / 64 K-tiles per plane */
#define WBT_BYTES  167772160UL      /* 4096*20480*2 : bf16 W^T (N x KP) */
#define XB_OFFSET  167772160UL      /* bf16 x (M x KP) after Wbt */
#define CP_OFFSET  251658240UL      /* 2x fp32 C-partials after xb */

typedef __attribute__((ext_vector_type(8))) short short8;
typedef __attribute__((ext_vector_type(4))) float float4v;
typedef __attribute__((ext_vector_type(8))) unsigned short ushort8;

__device__ __forceinline__ unsigned short f2bf_rne(float f) {
    union { float f; unsigned int u; } v; v.f = f;
    unsigned int u = v.u;
    u += 0x7FFFu + ((u >> 16) & 1u);   // round-to-nearest-even
    return (unsigned short)(u >> 16);
}

__device__ __forceinline__ float bf2f(unsigned short h) {
    union { unsigned int u; float f; } v;
    v.u = ((unsigned int)h) << 16;
    return v.f;
}

__device__ __forceinline__ void gload_lds16(const void* g, void* l) {
    __builtin_amdgcn_global_load_lds(
        (const __attribute__((address_space(1))) void*)g,
        (__attribute__((address_space(3))) void*)l, 16, 0, 0);
}

// ---- 1. scatter-add COO directly into bf16 W^T (N_DIM x KP row-major) ----
__global__ void scatter_bf16_kernel(const float* __restrict__ kv,
                                    const int* __restrict__ ind,
                                    unsigned int* __restrict__ W, int nnz) {
    int t = blockIdx.x * blockDim.x + threadIdx.x;
    if (t >= nnz) return;
    int r = ind[2 * t];      // input_dim index (K)
    int c = ind[2 * t + 1];  // units index (N)
    float v = kv[t];
    size_t elem = (size_t)c * KP + r;      // bf16 element index in W^T
    unsigned int* word = &W[elem >> 1];
    const bool hi = (elem & 1) != 0;       // KP even -> rows never straddle words
    unsigned int old = __atomic_load_n(word, __ATOMIC_RELAXED);
    unsigned int assumed;
    do {
        assumed = old;
        unsigned short h = hi ? (unsigned short)(assumed >> 16)
                              : (unsigned short)(assumed & 0xFFFFu);
        unsigned short nh = f2bf_rne(bf2f(h) + v);
        unsigned int nw = hi ? ((assumed & 0x0000FFFFu) | ((unsigned int)nh << 16))
                             : ((assumed & 0xFFFF0000u) | (unsigned int)nh);
        old = atomicCAS(word, assumed, nw);
    } while (old != assumed);
}

// ---- 2. fp32 -> bf16 convert for x, writes K-pad zeros itself ----
__global__ void convert_kernel(const float* __restrict__ src,
                               unsigned short* __restrict__ dst) {
    size_t t = (size_t)blockIdx.x * 256 + threadIdx.x;
    int row = (int)(t / 2560);
    int c8  = (int)(t % 2560);
    ushort8 o;
    if (c8 < 2500) {
        const float4* sv = (const float4*)(src + (size_t)row * K_DIM + (size_t)c8 * 8);
        float4 a = sv[0];
        float4 b = sv[1];
        o[0] = f2bf_rne(a.x); o[1] = f2bf_rne(a.y);
        o[2] = f2bf_rne(a.z); o[3] = f2bf_rne(a.w);
        o[4] = f2bf_rne(b.x); o[5] = f2bf_rne(b.y);
        o[6] = f2bf_rne(b.z); o[7] = f2bf_rne(b.w);
    } else {
        o = (ushort8)0;
    }
    *(ushort8*)(dst + (size_t)row * KP + (size_t)c8 * 8) = o;
}

// ---- 3. 256x256-tile split-K=2 GEMM, 4-phase/tile schedule, XOR-swizzled LDS ----
// A: M x KP bf16 row-major, Bt: N x KP bf16 row-major.
// 512 thr = 8 waves (2Mx4N), per-wave 128x64, BK=64 (one 128B row per tile-row).
// LDS 128 KiB = 2 bufs x (A 32KB: 256 rows x 128B | B 32KB).
// Swizzle: 16B chunk c of row r stored at slot c^(r&7). Within any 8
// consecutive read lanes (fixed quad, r16 consecutive), row-stride 128B
// contributes bank 0 and chunk^h is a bijection over 8 values -> the 8
// lanes cover all 32 banks: ZERO conflicts (HW-verified pattern, round 1).
// Staging: lane l fetches chunk (l&7)^(l>>3) of row w*8+(l>>3): each 8-lane
// group reads one full 128B line (permuted within the line) -> coalesced;
// LDS dest stays linear (gload_lds requirement).
// Schedule per tile t (buf = t&1): 4 phases (kh x mh), each {ds_read frags,
// stage one 16KB quarter, s_barrier, lgkmcnt(0), setprio(1) 16 MFMA
// setprio(0), [vmcnt(2) at P4 only], s_barrier}.  Quarters of tile T are
// issued at (T-2).P4 (qB0) and (T-1).P1/P2/P3 (qA0,qA1,qB1); the single
// per-tile vmcnt(2) at P4 waits tile T's 8 loads, leaving T+1.qB0 in
// flight -- vmcnt never drains in the main loop.  All same-phase
// stage/read LDS regions are disjoint; cross-phase safety follows from
// lgkmcnt(0) preceding each phase's end-barrier.
__global__ __launch_bounds__(512, 2) void gemm256_kernel(
    const unsigned short* __restrict__ A,
    const unsigned short* __restrict__ Bt,
    float* __restrict__ Cp) {

    __shared__ unsigned short L[65536];    // 131072 B

    const int t    = threadIdx.x;
    const int w    = t >> 6;
    const int l    = t & 63;
    const int quad = l >> 4;
    const int r16  = l & 15;
    const int wm   = w >> 2;               // 0..1
    const int wn   = w & 3;                // 0..3

    const int m0 = blockIdx.y * 256;
    const int n0 = blockIdx.x * 256;
    const size_t k0 = (size_t)blockIdx.z * KZ;

    // staging lane mapping: row sub-index lr8 = l>>3, chunk sl = (l&7)^(l>>3)
    const int lr8 = l >> 3;
    const int sl  = (l & 7) ^ lr8;
    const int w1024 = w << 10;

    // 8 global pointers: quarter q covers rows q*64 .. q*64+63 (2 gloads of
    // 8 rows/wave each handled by one pointer at +0 and one at +64 rows is
    // folded into q granularity: each pointer = one gload row-block of 64).
    const unsigned short* pA0 = A  + (size_t)(m0 +   0 + w * 8 + lr8) * KP + k0 + sl * 8;
    const unsigned short* pA1 = A  + (size_t)(m0 +  64 + w * 8 + lr8) * KP + k0 + sl * 8;
    const unsigned short* pA2 = A  + (size_t)(m0 + 128 + w * 8 + lr8) * KP + k0 + sl * 8;
    const unsigned short* pA3 = A  + (size_t)(m0 + 192 + w * 8 + lr8) * KP + k0 + sl * 8;
    const unsigned short* pB0 = Bt + (size_t)(n0 +   0 + w * 8 + lr8) * KP + k0 + sl * 8;
    const unsigned short* pB1 = Bt + (size_t)(n0 +  64 + w * 8 + lr8) * KP + k0 + sl * 8;
    const unsigned short* pB2 = Bt + (size_t)(n0 + 128 + w * 8 + lr8) * KP + k0 + sl * 8;
    const unsigned short* pB3 = Bt + (size_t)(n0 + 192 + w * 8 + lr8) * KP + k0 + sl * 8;

    char* Lb = (char*)L;

    // buffer layout (byte offsets): buf b at b*65536; A slab [0,32K), B [32K,64K)
    // gload-block q (64 rows) at q*8192 + w*1024 within the slab.
#define STG_A(OB, Q, P) do { \
    gload_lds16(P, Lb + (OB) + (Q) * 8192 + w1024); P += 64; } while (0)
#define STG_B(OB, Q, P) do { \
    gload_lds16(P, Lb + (OB) + 32768 + (Q) * 8192 + w1024); P += 64; } while (0)

    // read offsets: byte = row*128 + ((chunk)^(row&7))*16, chunk = kh*4+quad
    const int h   = r16 & 7;
    const int so0 = ((quad ^ h) << 4);          // kh = 0
    const int so1 = (((4 | quad) ^ h) << 4);    // kh = 1
    const int aoff = wm * 16384 + r16 * 128;    // + mh*8192 + i*2048
    const int boff = 32768 + wn * 8192 + r16 * 128;   // + j*2048

    float4v acc[8][4];
#pragma unroll
    for (int i = 0; i < 8; ++i)
#pragma unroll
        for (int j = 0; j < 4; ++j)
            acc[i][j] = (float4v){0.f, 0.f, 0.f, 0.f};

    short8 bfr[4], af[4];

#define VM2 asm volatile("s_waitcnt vmcnt(2)" ::: "memory")
#define VMNONE ((void)0)

#define PHASE(BUF, MH, SO, LOADB, STG, VM) do { \
    const char* base_ = Lb + (BUF); \
    if (LOADB) { \
        _Pragma("unroll") \
        for (int j = 0; j < 4; ++j) \
            bfr[j] = *(const short8*)(base_ + boff + j * 2048 + (SO)); \
    } \
    _Pragma("unroll") \
    for (int i = 0; i < 4; ++i) \
        af[i] = *(const short8*)(base_ + aoff + (MH) * 8192 + i * 2048 + (SO)); \
    STG; \
    __builtin_amdgcn_s_barrier(); \
    asm volatile("s_waitcnt lgkmcnt(0)" ::: "memory"); \
    __builtin_amdgcn_s_setprio(1); \
    _Pragma("unroll") \
    for (int i = 0; i < 4; ++i) \
        _Pragma("unroll") \
        for (int j = 0; j < 4; ++j) \
            acc[(MH) * 4 + i][j] = __builtin_amdgcn_mfma_f32_16x16x32_bf16( \
                af[i], bfr[j], acc[(MH) * 4 + i][j], 0, 0, 0); \
    __builtin_amdgcn_s_setprio(0); \
    VM; \
    __builtin_amdgcn_s_barrier(); \
} while (0)

    // one tile = 4 phases; stages: P1 qA0(t+1->OB), P2 qA1(t+1->OB),
    // P3 qB1(t+1->OB), P4 qB0(t+2->BUF) + vmcnt(2).
#define TILE(BUF, OB) do { \
    PHASE(BUF, 0, so0, true,  { STG_A(OB, 0, pA0); STG_A(OB, 1, pA1); }, VMNONE); \
    PHASE(BUF, 1, so0, false, { STG_A(OB, 2, pA2); STG_A(OB, 3, pA3); }, VMNONE); \
    PHASE(BUF, 0, so1, true,  { STG_B(OB, 2, pB2); STG_B(OB, 3, pB3); }, VMNONE); \
    PHASE(BUF, 1, so1, false, { STG_B(BUF, 0, pB0); STG_B(BUF, 1, pB1); }, VM2); \
} while (0)

    // prologue: tile0 full (8 gloads) into buf0 + tile1.qB0 (2) into buf1;
    // vmcnt(2) waits tile0's 8, leaves tile1.qB0 in flight (= loop steady state).
    STG_A(0, 0, pA0); STG_A(0, 1, pA1); STG_A(0, 2, pA2); STG_A(0, 3, pA3);
    STG_B(0, 0, pB0); STG_B(0, 1, pB1); STG_B(0, 2, pB2); STG_B(0, 3, pB3);
    STG_B(65536, 0, pB0); STG_B(65536, 1, pB1);
    asm volatile("s_waitcnt vmcnt(2)" ::: "memory");
    __builtin_amdgcn_s_barrier();

    // 160 tiles = 80 iterations x 2 (buf0 tile, buf1 tile).
    // Tail stages overrun K by <=2 tiles: reads land in the adjacent
    // workspace region (xb / Cp, allocated), data never consumed.
#pragma unroll 1
    for (int it = 0; it < NTILE / 2; ++it) {
        TILE(0, 65536);
        TILE(65536, 0);
    }
    // drain in-flight LDS DMA before wave exit
    asm volatile("s_waitcnt vmcnt(0)" ::: "memory");

    // epilogue: raw fp32 partial; C/D layout: col = lane&15, row = quad*4 + reg
    float* Cz = Cp + (size_t)blockIdx.z * ((size_t)M_DIM * N_DIM);
#pragma unroll
    for (int i = 0; i < 8; ++i) {
        const int row = m0 + wm * 128 + i * 16 + quad * 4;
#pragma unroll
        for (int j = 0; j < 4; ++j) {
            const int col = n0 + wn * 64 + j * 16 + r16;
#pragma unroll
            for (int r = 0; r < 4; ++r)
                Cz[(size_t)(row + r) * N_DIM + col] = acc[i][j][r];
        }
    }
#undef TILE
#undef PHASE
#undef STG_A
#undef STG_B
#undef VM2
#undef VMNONE
}

// ---- 4. combine: out = tanh(C0 + C1 + bias), float4 vectorized ----
__global__ void combine_kernel(const float* __restrict__ Cp,
                               const float* __restrict__ bias,
                               float* __restrict__ out) {
    size_t t = (size_t)blockIdx.x * 256 + threadIdx.x;       // per float4
    const size_t stride = (size_t)M_DIM * N_DIM / 4;
    float4 a = ((const float4*)Cp)[t];
    float4 b = ((const float4*)Cp)[t + stride];
    float4 bv = ((const float4*)bias)[t & (N_DIM / 4 - 1)];
    float4 o;
    o.x = tanhf(a.x + b.x + bv.x);
    o.y = tanhf(a.y + b.y + bv.y);
    o.z = tanhf(a.z + b.z + bv.z);
    o.w = tanhf(a.w + b.w + bv.w);
    ((float4*)out)[t] = o;
}

extern "C" void kernel_launch(void* const* d_in, const int* in_sizes, int n_in,
                              void* d_out, int out_size, void* d_ws, size_t ws_size,
                              hipStream_t stream) {
    const float* x    = (const float*)d_in[0];
    const float* kv   = (const float*)d_in[1];
    const float* bias = (const float*)d_in[2];
    const int*   ind  = (const int*)d_in[3];
    const int nnz = in_sizes[1];

    unsigned short* Wbt = (unsigned short*)d_ws;                        // bf16 W^T (N x KP)
    unsigned short* xb  = (unsigned short*)((char*)d_ws + XB_OFFSET);   // bf16 x (M x KP)
    float* Cp = (float*)((char*)d_ws + CP_OFFSET);                      // 2 x 33.55 MB partials

    // 1. zero bf16 W^T (incl. K-pad)
    hipMemsetAsync(Wbt, 0, WBT_BYTES, stream);
    // 2. scatter-add straight into bf16 W^T (CAS on 16-bit halves)
    scatter_bf16_kernel<<<(nnz + 255) / 256, 256, 0, stream>>>(
        kv, ind, (unsigned int*)Wbt, nnz);
    // 3. x fp32 -> bf16 (writes its own K-pad zeros)
    convert_kernel<<<(M_DIM * (KP / 8)) / 256, 256, 0, stream>>>(x, xb);
    // 4. split-K=2 GEMM partials, 256x256 tiles, 1 WG/CU
    gemm256_kernel<<<dim3(N_DIM / 256, M_DIM / 256, 2), 512, 0, stream>>>(
        xb, Wbt, Cp);
    // 5. combine + bias + tanh
    combine_kernel<<<(M_DIM * N_DIM) / (256 * 4), 256, 0, stream>>>(
        Cp, bias, (float*)d_out);
}